// Round 12
// baseline (389.425 us; speedup 1.0000x reference)
//
#include <hip/hip_runtime.h>

#define SCALE 0.125f

constexpr int L_ = 1024, T_ = 1024, D_ = 64, HB_ = 64;

using f32x4 = __attribute__((ext_vector_type(4))) float;
using half8 = __attribute__((ext_vector_type(8))) _Float16;
using half4 = __attribute__((ext_vector_type(4))) _Float16;

// lgkm-only barrier: orders LDS producer/consumer without draining vmem.
#define BARRIER() asm volatile("s_waitcnt lgkmcnt(0)\n\ts_barrier" ::: "memory")

// ===========================================================================
// Prologue 1: K f32 -> Kh f16, same [hb][t][d] layout. (r10-proven)
// ===========================================================================
__global__ __launch_bounds__(256) void cvt_k(const float* __restrict__ k,
                                             _Float16* __restrict__ kh) {
  const size_t i = ((size_t)blockIdx.x * 256 + threadIdx.x) * 8;
  f32x4 a = *(const f32x4*)(k + i);
  f32x4 b = *(const f32x4*)(k + i + 4);
  half8 h;
#pragma unroll
  for (int e = 0; e < 4; ++e) {
    h[e] = (_Float16)a[e];
    h[4 + e] = (_Float16)b[e];
  }
  *(half8*)(kh + i) = h;
}

// ===========================================================================
// Prologue 2: V f32 [hb][t][d] -> Vh f16 transposed [hb][d][t]. (r10-proven)
// ===========================================================================
__global__ __launch_bounds__(256) void cvt_v(const float* __restrict__ v,
                                             _Float16* __restrict__ vh) {
  __shared__ _Float16 ts[64][136];
  const int tid = threadIdx.x;
  const int hb = blockIdx.y;
  const int t0 = blockIdx.x * 128;
  {
    const int tr = tid >> 1, dh = (tid & 1) * 32;
    const float* p = v + ((size_t)hb * T_ + t0 + tr) * D_ + dh;
#pragma unroll
    for (int i = 0; i < 8; ++i) {
      f32x4 r = *(const f32x4*)(p + i * 4);
#pragma unroll
      for (int e = 0; e < 4; ++e) ts[dh + i * 4 + e][tr] = (_Float16)r[e];
    }
  }
  __syncthreads();
  {
    const int d = tid >> 2, tq = (tid & 3) * 32;
    _Float16* qo = vh + ((size_t)hb * D_ + d) * T_ + t0 + tq;
#pragma unroll
    for (int i = 0; i < 4; ++i)
      *(half8*)(qo + i * 8) = *(const half8*)&ts[d][tq + i * 8];
  }
}

// ===========================================================================
// Pass 1 (zpass): 64 q-rows/block; wave w owns rows w*16..+15 and covers ALL
// 64 t of each chunk via the nt=0..3 inner loop (r5-validated coverage).
// Swapped QK^T from LDS-staged f16 K tile (double-buffered, 1 lgkm
// barrier/chunk). prev = 4x dwordx4/chunk, depth-1 double-buffered.
// E = exp(score) f16 -> upper half of att rows. 1/Z -> out[qrow*D] (d=0
// slot; read then overwritten by pvpass).
// ===========================================================================
__global__ __launch_bounds__(256, 6) void zpass(
    const float* __restrict__ q, const _Float16* __restrict__ Kh,
    const float* __restrict__ prev, float* __restrict__ out,
    float* __restrict__ att) {
  __shared__ __align__(16) _Float16 Ks[2][64][72];

  const int ltile = blockIdx.x, hb = blockIdx.y;
  const int tid = threadIdx.x;
  const int w = tid >> 6, l = tid & 63, l15 = l & 15, lg = l >> 4;
  const int qrow = ltile * 64 + w * 16 + l15;

  // Q B-frag (swapped QK^T): lane holds Q[qrow][f*32 + lg*8 + e]
  half8 qb2[2];
  {
    const float* qp = q + ((size_t)hb * L_ + qrow) * D_ + lg * 8;
#pragma unroll
    for (int f = 0; f < 2; ++f)
#pragma unroll
      for (int e = 0; e < 8; ++e) qb2[f][e] = (_Float16)qp[f * 32 + e];
  }

  const float* prow = prev + ((size_t)hb * L_ + qrow) * (size_t)T_;
  const _Float16* kb = Kh + (size_t)hb * T_ * D_;
  _Float16* erow =
      (_Float16*)(att + ((size_t)hb * L_ + qrow) * (size_t)T_) + T_;

  // K staging: f16 tile 64t x 64d = 8KB; thread -> row sr, 32B (2x half8)
  const int sr = tid >> 2, sc = (tid & 3) * 16;
  half8 kst[2][2];
  auto kload = [&](int c, int s) {
    const _Float16* p = kb + (size_t)(c * 64 + sr) * D_ + sc;
    kst[s][0] = *(const half8*)p;
    kst[s][1] = *(const half8*)(p + 8);
  };
  auto kwrite = [&](int buf, int s) {
    *(half8*)&Ks[buf][sr][sc] = kst[s][0];
    *(half8*)&Ks[buf][sr][sc + 8] = kst[s][1];
  };
  // prev: 4 x dwordx4 per chunk (t = c*64 + nt*16 + lg*4), double-buffered
  f32x4 pb[2][4];
  auto pload = [&](int c, int s) {
#pragma unroll
    for (int nt = 0; nt < 4; ++nt)
      pb[s][nt] = *(const f32x4*)(prow + c * 64 + nt * 16 + lg * 4);
  };

  kload(0, 0);
  pload(0, 0);
  kwrite(0, 0);
  kload(1, 1);
  pload(1, 1);

  float zsum = 0.f;

#pragma unroll 4
  for (int c = 0; c < 16; ++c) {
    BARRIER();                        // Ks[c&1] staged for all waves
    // copy this chunk's prev to locals before the buffer is reissued
    f32x4 pvv[4];
#pragma unroll
    for (int nt = 0; nt < 4; ++nt) pvv[nt] = pb[c & 1][nt];
    if (c < 14) { kload(c + 2, c & 1); pload(c + 2, c & 1); }
    if (c < 15) kwrite((c + 1) & 1, (c + 1) & 1);  // other buffer: safe

#pragma unroll
    for (int nt = 0; nt < 4; ++nt) {
      // swapped QK^T: acc[i] = S^T[t = c*64 + nt*16 + lg*4 + i][q = qrow]
      const int trow = nt * 16 + l15;
      half8 ka0 = *(const half8*)&Ks[c & 1][trow][lg * 8];
      half8 ka1 = *(const half8*)&Ks[c & 1][trow][32 + lg * 8];
      f32x4 acc = {0.f, 0.f, 0.f, 0.f};
      acc = __builtin_amdgcn_mfma_f32_16x16x32_f16(ka0, qb2[0], acc, 0, 0, 0);
      acc = __builtin_amdgcn_mfma_f32_16x16x32_f16(ka1, qb2[1], acc, 0, 0, 0);

      float e0 = __expf(acc[0] * SCALE + pvv[nt][0]);
      float e1 = __expf(acc[1] * SCALE + pvv[nt][1]);
      float e2 = __expf(acc[2] * SCALE + pvv[nt][2]);
      float e3 = __expf(acc[3] * SCALE + pvv[nt][3]);
      zsum += (e0 + e1) + (e2 + e3);
      half4 ev;
      ev[0] = (_Float16)e0; ev[1] = (_Float16)e1;
      ev[2] = (_Float16)e2; ev[3] = (_Float16)e3;
      *(half4*)(erow + c * 64 + nt * 16 + lg * 4) = ev;
    }
  }

  // Z: reduce over the 4 lg lanes sharing each q-row; store reciprocal
  zsum += __shfl_xor(zsum, 16, 64);
  zsum += __shfl_xor(zsum, 32, 64);
  if (lg == 0) out[((size_t)hb * L_ + qrow) * (size_t)D_] = 1.0f / zsum;
}

// ===========================================================================
// Pass 2 (pvpass): E f16 A-frags direct (16B), normalize, coalesced att f32
// stores from regs, PV MFMA with LDS-staged f16 V^T tile (double-buffered,
// 1 barrier/chunk). rz read from out d=0 slots (same-wave rows only), then
// out overwritten. In-place: att writes of chunk c clobber E chunks
// <= 2c-15, all consumed by then (r4/r5-validated scheme).
// ===========================================================================
__global__ __launch_bounds__(256, 6) void pvpass(
    const _Float16* __restrict__ Vh, float* __restrict__ out,
    float* __restrict__ att) {
  __shared__ __align__(16) _Float16 Vt[2][64][72];

  const int ltile = blockIdx.x, hb = blockIdx.y;
  const int tid = threadIdx.x;
  const int w = tid >> 6, l = tid & 63, l15 = l & 15, lg = l >> 4;
  const int qrow = ltile * 64 + w * 16 + l15;

  float* arow = att + ((size_t)hb * L_ + qrow) * (size_t)T_;
  const _Float16* erow = (const _Float16*)arow + T_;
  const float rzq = out[((size_t)hb * L_ + qrow) * (size_t)D_];
  const _Float16* vbh = Vh + (size_t)hb * D_ * T_;  // [d][t] f16

  // V^T staging: tile 64d x 64t f16 = 8KB; thread -> d-row sr, 32B
  const int sr = tid >> 2, sc = (tid & 3) * 16;
  half8 vst[2][2];
  auto vload = [&](int c, int s) {
    const _Float16* p = vbh + (size_t)sr * T_ + c * 64 + sc;
    vst[s][0] = *(const half8*)p;
    vst[s][1] = *(const half8*)(p + 8);
  };
  auto vwrite = [&](int buf, int s) {
    *(half8*)&Vt[buf][sr][sc] = vst[s][0];
    *(half8*)&Vt[buf][sr][sc + 8] = vst[s][1];
  };
  half8 eb[2][2];
  auto eload = [&](int c, int s) {
    eb[s][0] = *(const half8*)(erow + c * 64 + lg * 8);
    eb[s][1] = *(const half8*)(erow + c * 64 + 32 + lg * 8);
  };

  vload(0, 0);
  eload(0, 0);
  vwrite(0, 0);
  vload(1, 1);
  eload(1, 1);

  f32x4 oacc[4];
#pragma unroll
  for (int nd = 0; nd < 4; ++nd) oacc[nd] = (f32x4){0.f, 0.f, 0.f, 0.f};

#pragma unroll 4
  for (int c = 0; c < 16; ++c) {
    BARRIER();                        // Vt[c&1] staged for all waves
    half8 e0 = eb[c & 1][0], e1 = eb[c & 1][1];  // copy before reissue
    if (c < 14) { vload(c + 2, c & 1); eload(c + 2, c & 1); }
    if (c < 15) vwrite((c + 1) & 1, (c + 1) & 1);

    // normalize + att store (direct from regs) + A-frags; PV MFMA
#pragma unroll
    for (int ks = 0; ks < 2; ++ks) {
      half8 ef = ks ? e1 : e0;
      f32x4 s0, s1;
      half8 af;
#pragma unroll
      for (int e = 0; e < 4; ++e) {
        float v0 = (float)ef[e] * rzq;
        float v1 = (float)ef[4 + e] * rzq;
        s0[e] = v0; s1[e] = v1;
        af[e] = (_Float16)v0;
        af[4 + e] = (_Float16)v1;
      }
      *(f32x4*)(arow + c * 64 + ks * 32 + lg * 8) = s0;
      *(f32x4*)(arow + c * 64 + ks * 32 + lg * 8 + 4) = s1;

#pragma unroll
      for (int nd = 0; nd < 4; ++nd) {
        half8 vb = *(const half8*)&Vt[c & 1][nd * 16 + l15][ks * 32 + lg * 8];
        oacc[nd] =
            __builtin_amdgcn_mfma_f32_16x16x32_f16(af, vb, oacc[nd], 0, 0, 0);
      }
    }
  }

  // epilogue: O already normalized. oacc[nd][i] = O[w*16+lg*4+i][nd*16+l15]
  float* outw =
      out + ((size_t)hb * L_ + ltile * 64 + w * 16 + lg * 4) * (size_t)D_;
#pragma unroll
  for (int nd = 0; nd < 4; ++nd)
#pragma unroll
    for (int i = 0; i < 4; ++i)
      outw[(size_t)i * D_ + nd * 16 + l15] = oacc[nd][i];
}

extern "C" void kernel_launch(void* const* d_in, const int* in_sizes, int n_in,
                              void* d_out, int out_size, void* d_ws,
                              size_t ws_size, hipStream_t stream) {
  const float* q    = (const float*)d_in[0];  // (H,B,L,D)
  const float* k    = (const float*)d_in[1];  // (H,B,T,D)
  const float* v    = (const float*)d_in[2];  // (H,B,T,D)
  const float* prev = (const float*)d_in[3];  // (H,B,L,T)

  float* out = (float*)d_out;                 // (H,B,L,D)
  float* att = out + (size_t)HB_ * L_ * D_;   // (H,B,L,T)

  const size_t KV_ELEMS = (size_t)HB_ * T_ * D_;  // 4,194,304
  _Float16* Kh = (_Float16*)d_ws;                 // 8 MB
  _Float16* Vh = Kh + KV_ELEMS;                   // 8 MB (ws >= 16 MB proven)

  cvt_k<<<(int)(KV_ELEMS / (256 * 8)), 256, 0, stream>>>(k, Kh);
  cvt_v<<<dim3(T_ / 128, HB_), 256, 0, stream>>>(v, Vh);

  dim3 grid(L_ / 64, HB_);
  zpass<<<grid, 256, 0, stream>>>(q, Kh, prev, out, att);
  pvpass<<<grid, 256, 0, stream>>>(Vh, out, att);
}

// Round 13
// 328.650 us; speedup vs baseline: 1.1849x; 1.1849x over previous
//
#include <hip/hip_runtime.h>

#define SCALE 0.125f

constexpr int L_ = 1024, T_ = 1024, D_ = 64, HB_ = 64;

using f32x4 = __attribute__((ext_vector_type(4))) float;
using half8 = __attribute__((ext_vector_type(8))) _Float16;
using half4 = __attribute__((ext_vector_type(4))) _Float16;

// ===========================================================================
// Prologue 1: K f32 -> Kh f16, same [hb][t][d] layout. (r10-proven)
// ===========================================================================
__global__ __launch_bounds__(256) void cvt_k(const float* __restrict__ k,
                                             _Float16* __restrict__ kh) {
  const size_t i = ((size_t)blockIdx.x * 256 + threadIdx.x) * 8;
  f32x4 a = *(const f32x4*)(k + i);
  f32x4 b = *(const f32x4*)(k + i + 4);
  half8 h;
#pragma unroll
  for (int e = 0; e < 4; ++e) {
    h[e] = (_Float16)a[e];
    h[4 + e] = (_Float16)b[e];
  }
  *(half8*)(kh + i) = h;
}

// ===========================================================================
// Prologue 2: V f32 [hb][t][d] -> Vh f16 transposed [hb][d][t]. (r10-proven)
// ===========================================================================
__global__ __launch_bounds__(256) void cvt_v(const float* __restrict__ v,
                                             _Float16* __restrict__ vh) {
  __shared__ _Float16 ts[64][136];
  const int tid = threadIdx.x;
  const int hb = blockIdx.y;
  const int t0 = blockIdx.x * 128;
  {
    const int tr = tid >> 1, dh = (tid & 1) * 32;
    const float* p = v + ((size_t)hb * T_ + t0 + tr) * D_ + dh;
#pragma unroll
    for (int i = 0; i < 8; ++i) {
      f32x4 r = *(const f32x4*)(p + i * 4);
#pragma unroll
      for (int e = 0; e < 4; ++e) ts[dh + i * 4 + e][tr] = (_Float16)r[e];
    }
  }
  __syncthreads();
  {
    const int d = tid >> 2, tq = (tid & 3) * 32;
    _Float16* qo = vh + ((size_t)hb * D_ + d) * T_ + t0 + tq;
#pragma unroll
    for (int i = 0; i < 4; ++i)
      *(half8*)(qo + i * 8) = *(const half8*)&ts[d][tq + i * 8];
  }
}

// ===========================================================================
// Pass 1 (zpass): 32 q-rows/block, grid 2048. Wave w: row-group rgrp=w&1
// (16 rows), t-half thalf=w>>1 (512 t). NO barriers in the loop:
//  - K frags direct from f16 Kh (L2/L3-hot, 64B-run loads)
//  - prev f32x4 depth-2 register prefetch (nothing drains it)
//  - E chunk -> wave-private LDS tile -> copy-out 32B/lane in 128B runs
//    (full-line stores; fixes r12's 4.4x write amplification)
// Z cross-wave via LDS + single end barrier. 1/Z -> out d=0 slots.
// ===========================================================================
__global__ __launch_bounds__(256, 6) void zpass(
    const float* __restrict__ q, const _Float16* __restrict__ Kh,
    const float* __restrict__ prev, float* __restrict__ out,
    float* __restrict__ att) {
  __shared__ __align__(16) _Float16 El[4][16][72];  // wave-private tiles
  __shared__ float zb[4][16];

  const int ltile = blockIdx.x;   // 0..31 (32-row tiles)
  const int hb    = blockIdx.y;   // 0..63
  const int tid = threadIdx.x;
  const int w = tid >> 6, l = tid & 63, l15 = l & 15, lg = l >> 4;
  const int rgrp = w & 1, thalf = w >> 1;
  const int qrow = ltile * 32 + rgrp * 16 + l15;

  // Q B-frag (swapped QK^T): lane holds Q[qrow][f*32 + lg*8 + e]
  half8 qb2[2];
  {
    const float* qp = q + ((size_t)hb * L_ + qrow) * D_ + lg * 8;
#pragma unroll
    for (int f = 0; f < 2; ++f)
#pragma unroll
      for (int e = 0; e < 8; ++e) qb2[f][e] = (_Float16)qp[f * 32 + e];
  }

  const float* prow =
      prev + ((size_t)hb * L_ + qrow) * (size_t)T_ + thalf * 512;
  const _Float16* kb = Kh + (size_t)hb * T_ * D_;

  f32x4 pb[2][4];
  auto pload = [&](int c, int s) {
#pragma unroll
    for (int nt = 0; nt < 4; ++nt)
      pb[s][nt] = *(const f32x4*)(prow + c * 64 + nt * 16 + lg * 4);
  };
  pload(0, 0);
  pload(1, 1);

  // copy-out mapping: lane -> row l>>2, col span (l&3)*16 (32B)
  const int cr = l >> 2, cc = (l & 3) * 16;
  _Float16* eprow =
      (_Float16*)(att +
                  ((size_t)hb * L_ + ltile * 32 + rgrp * 16 + cr) * (size_t)T_) +
      T_ + thalf * 512 + cc;

  float zsum = 0.f;

#pragma unroll 2
  for (int c = 0; c < 8; ++c) {
    f32x4 pvv[4];
#pragma unroll
    for (int nt = 0; nt < 4; ++nt) pvv[nt] = pb[c & 1][nt];
    if (c < 6) pload(c + 2, c & 1);

#pragma unroll
    for (int nt = 0; nt < 4; ++nt) {
      // swapped QK^T: acc[i] = S^T[t = t0 + nt*16 + lg*4 + i][q = qrow]
      const int trow = thalf * 512 + c * 64 + nt * 16 + l15;
      half8 ka0 = *(const half8*)(kb + (size_t)trow * D_ + lg * 8);
      half8 ka1 = *(const half8*)(kb + (size_t)trow * D_ + 32 + lg * 8);
      f32x4 acc = {0.f, 0.f, 0.f, 0.f};
      acc = __builtin_amdgcn_mfma_f32_16x16x32_f16(ka0, qb2[0], acc, 0, 0, 0);
      acc = __builtin_amdgcn_mfma_f32_16x16x32_f16(ka1, qb2[1], acc, 0, 0, 0);

      float e0 = __expf(acc[0] * SCALE + pvv[nt][0]);
      float e1 = __expf(acc[1] * SCALE + pvv[nt][1]);
      float e2 = __expf(acc[2] * SCALE + pvv[nt][2]);
      float e3 = __expf(acc[3] * SCALE + pvv[nt][3]);
      zsum += (e0 + e1) + (e2 + e3);
      half4 ev;
      ev[0] = (_Float16)e0; ev[1] = (_Float16)e1;
      ev[2] = (_Float16)e2; ev[3] = (_Float16)e3;
      *(half4*)&El[w][l15][nt * 16 + lg * 4] = ev;
    }

    // wave-private copy-out (same-wave DS pipe is in-order: reads see writes)
    half8 ha = *(const half8*)&El[w][cr][cc];
    half8 hb2 = *(const half8*)&El[w][cr][cc + 8];
    *(half8*)(eprow + c * 64) = ha;
    *(half8*)(eprow + c * 64 + 8) = hb2;
  }

  // Z: reduce 4 lg lanes per row, then cross-wave (two t-halves)
  zsum += __shfl_xor(zsum, 16, 64);
  zsum += __shfl_xor(zsum, 32, 64);
  if (lg == 0) zb[w][l15] = zsum;
  __syncthreads();
  if (tid < 32) {
    const float z = zb[tid >> 4][tid & 15] + zb[2 + (tid >> 4)][tid & 15];
    out[((size_t)hb * L_ + ltile * 32 + tid) * (size_t)D_] = 1.0f / z;
  }
}

// ===========================================================================
// Pass 2 (pvpass): 64 q-rows/block, grid 1024. ZERO LDS, ZERO barriers.
// E f16 A-frags direct (16B, full-line groups) with depth-4 prefetch;
// V direct from transposed f16 Vh (L2/L3-hot); normalize in f32; att f32
// stores 32B/lane in 128B runs (full lines). In-place E-clobber safe:
// prefetch c+4 reads f32 cols 512+32(c+4)..+32, stores cover cols <64c+64;
// overlap requires c>18 (max 15). rz from out d=0, overwritten at end.
// ===========================================================================
__global__ __launch_bounds__(256, 4) void pvpass(
    const _Float16* __restrict__ Vh, float* __restrict__ out,
    float* __restrict__ att) {
  const int ltile = blockIdx.x;   // 0..15
  const int hb    = blockIdx.y;   // 0..63
  const int tid = threadIdx.x;
  const int w = tid >> 6, l = tid & 63, l15 = l & 15, lg = l >> 4;
  const int qrow = ltile * 64 + w * 16 + l15;

  float* arow = att + ((size_t)hb * L_ + qrow) * (size_t)T_;
  const _Float16* erow = (const _Float16*)arow + T_;
  const float rzq = out[((size_t)hb * L_ + qrow) * (size_t)D_];
  const _Float16* vbh = Vh + (size_t)hb * D_ * T_;  // [d][t] f16

  half8 eb[4][2];  // depth-4 E prefetch, statically indexed
  auto eload = [&](int c, int s) {
    eb[s][0] = *(const half8*)(erow + c * 64 + lg * 8);
    eb[s][1] = *(const half8*)(erow + c * 64 + 32 + lg * 8);
  };
  eload(0, 0); eload(1, 1); eload(2, 2); eload(3, 3);

  f32x4 oacc[4];
#pragma unroll
  for (int nd = 0; nd < 4; ++nd) oacc[nd] = (f32x4){0.f, 0.f, 0.f, 0.f};

#pragma unroll 4
  for (int c = 0; c < 16; ++c) {
    half8 e0 = eb[c & 3][0], e1 = eb[c & 3][1];
    if (c < 12) eload(c + 4, c & 3);

#pragma unroll
    for (int ks = 0; ks < 2; ++ks) {
      half8 ef = ks ? e1 : e0;
      f32x4 s0, s1;
      half8 af;
#pragma unroll
      for (int e = 0; e < 4; ++e) {
        float v0 = (float)ef[e] * rzq;
        float v1 = (float)ef[4 + e] * rzq;
        s0[e] = v0; s1[e] = v1;
        af[e] = (_Float16)v0;
        af[4 + e] = (_Float16)v1;
      }
      *(f32x4*)(arow + c * 64 + ks * 32 + lg * 8) = s0;
      *(f32x4*)(arow + c * 64 + ks * 32 + lg * 8 + 4) = s1;

#pragma unroll
      for (int nd = 0; nd < 4; ++nd) {
        half8 vb = *(const half8*)(vbh + (size_t)(nd * 16 + l15) * T_ +
                                   c * 64 + ks * 32 + lg * 8);
        oacc[nd] =
            __builtin_amdgcn_mfma_f32_16x16x32_f16(af, vb, oacc[nd], 0, 0, 0);
      }
    }
  }

  // epilogue: oacc[nd][i] = O[w*16+lg*4+i][nd*16+l15] (already normalized)
  float* outw =
      out + ((size_t)hb * L_ + ltile * 64 + w * 16 + lg * 4) * (size_t)D_;
#pragma unroll
  for (int nd = 0; nd < 4; ++nd)
#pragma unroll
    for (int i = 0; i < 4; ++i)
      outw[(size_t)i * D_ + nd * 16 + l15] = oacc[nd][i];
}

extern "C" void kernel_launch(void* const* d_in, const int* in_sizes, int n_in,
                              void* d_out, int out_size, void* d_ws,
                              size_t ws_size, hipStream_t stream) {
  const float* q    = (const float*)d_in[0];  // (H,B,L,D)
  const float* k    = (const float*)d_in[1];  // (H,B,T,D)
  const float* v    = (const float*)d_in[2];  // (H,B,T,D)
  const float* prev = (const float*)d_in[3];  // (H,B,L,T)

  float* out = (float*)d_out;                 // (H,B,L,D)
  float* att = out + (size_t)HB_ * L_ * D_;   // (H,B,L,T)

  const size_t KV_ELEMS = (size_t)HB_ * T_ * D_;  // 4,194,304
  _Float16* Kh = (_Float16*)d_ws;                 // 8 MB
  _Float16* Vh = Kh + KV_ELEMS;                   // 8 MB (ws >= 16 MB proven)

  cvt_k<<<(int)(KV_ELEMS / (256 * 8)), 256, 0, stream>>>(k, Kh);
  cvt_v<<<dim3(T_ / 128, HB_), 256, 0, stream>>>(v, Vh);

  zpass<<<dim3(L_ / 32, HB_), 256, 0, stream>>>(q, Kh, prev, out, att);
  pvpass<<<dim3(L_ / 64, HB_), 256, 0, stream>>>(Vh, out, att);
}

// Round 14
// 259.141 us; speedup vs baseline: 1.5028x; 1.2682x over previous
//
#include <hip/hip_runtime.h>

#define SCALE 0.125f

constexpr int L_ = 1024, T_ = 1024, D_ = 64, HB_ = 64;

using f32x4 = __attribute__((ext_vector_type(4))) float;
using half8 = __attribute__((ext_vector_type(8))) _Float16;
using half4 = __attribute__((ext_vector_type(4))) _Float16;

// ===========================================================================
// Prologue 1: K f32 -> Kh f16, same [hb][t][d] layout. (r10-proven)
// ===========================================================================
__global__ __launch_bounds__(256) void cvt_k(const float* __restrict__ k,
                                             _Float16* __restrict__ kh) {
  const size_t i = ((size_t)blockIdx.x * 256 + threadIdx.x) * 8;
  f32x4 a = *(const f32x4*)(k + i);
  f32x4 b = *(const f32x4*)(k + i + 4);
  half8 h;
#pragma unroll
  for (int e = 0; e < 4; ++e) {
    h[e] = (_Float16)a[e];
    h[4 + e] = (_Float16)b[e];
  }
  *(half8*)(kh + i) = h;
}

// ===========================================================================
// Prologue 2: V f32 [hb][t][d] -> Vh f16 transposed [hb][d][t]. (r10-proven)
// ===========================================================================
__global__ __launch_bounds__(256) void cvt_v(const float* __restrict__ v,
                                             _Float16* __restrict__ vh) {
  __shared__ _Float16 ts[64][136];
  const int tid = threadIdx.x;
  const int hb = blockIdx.y;
  const int t0 = blockIdx.x * 128;
  {
    const int tr = tid >> 1, dh = (tid & 1) * 32;
    const float* p = v + ((size_t)hb * T_ + t0 + tr) * D_ + dh;
#pragma unroll
    for (int i = 0; i < 8; ++i) {
      f32x4 r = *(const f32x4*)(p + i * 4);
#pragma unroll
      for (int e = 0; e < 4; ++e) ts[dh + i * 4 + e][tr] = (_Float16)r[e];
    }
  }
  __syncthreads();
  {
    const int d = tid >> 2, tq = (tid & 3) * 32;
    _Float16* qo = vh + ((size_t)hb * D_ + d) * T_ + t0 + tq;
#pragma unroll
    for (int i = 0; i < 4; ++i)
      *(half8*)(qo + i * 8) = *(const half8*)&ts[d][tq + i * 8];
  }
}

// ===========================================================================
// Pass 1 (zpass): 512 threads (8 waves), 128 q-rows/block, grid 8x64.
// The ENTIRE per-hb K (f16, [1024][70] = 140KB LDS) is staged ONCE; the main
// loop's vmem queue holds ONLY the prev stream + E stores, so prev consume-
// waits drain nothing but older prev (in-order vmcnt is now harmless) and
// MFMA operands arrive via lgkm (independent counter). E copy-out goes
// through a wave-private LDS tile and is written as dense 64B sectors.
// 1/Z -> out d=0 slots (read then overwritten by pvpass).
// ===========================================================================
__global__ __launch_bounds__(512) void zpass(
    const float* __restrict__ q, const _Float16* __restrict__ Kh,
    const float* __restrict__ prev, float* __restrict__ out,
    float* __restrict__ att) {
  __shared__ __align__(16) _Float16 Ks[1024][70];    // 140 KB, full-T K
  __shared__ __align__(16) _Float16 El[8][16][72];   // 18 KB wave-private E

  const int ltile = blockIdx.x;   // 0..7 (128-row tiles)
  const int hb    = blockIdx.y;   // 0..63
  const int tid = threadIdx.x;
  const int w = tid >> 6, l = tid & 63, l15 = l & 15, lg = l >> 4;
  const int qrow = ltile * 128 + w * 16 + l15;

  const _Float16* kbase = Kh + (size_t)hb * T_ * D_;

  // ---- stage ALL of K for this hb: 8 reps x (512 thr x 32B) = 128 KB
  {
    const int srow = tid >> 2, scol = (tid & 3) * 16;
#pragma unroll
    for (int rep = 0; rep < 8; ++rep) {
      const int r = rep * 128 + srow;
      half8 a = *(const half8*)(kbase + (size_t)r * D_ + scol);
      half8 b = *(const half8*)(kbase + (size_t)r * D_ + scol + 8);
      *(half8*)&Ks[r][scol] = a;
      *(half8*)&Ks[r][scol + 8] = b;
    }
  }

  // Q B-frag (swapped QK^T): lane holds Q[qrow][f*32 + lg*8 + e]
  half8 qb2[2];
  {
    const float* qp = q + ((size_t)hb * L_ + qrow) * D_ + lg * 8;
#pragma unroll
    for (int f = 0; f < 2; ++f)
#pragma unroll
      for (int e = 0; e < 8; ++e) qb2[f][e] = (_Float16)qp[f * 32 + e];
  }

  const float* prow = prev + ((size_t)hb * L_ + qrow) * (size_t)T_;
  // E copy-out: lane -> row cr (within wave's 16), dense 64B sectors
  const int cr = l >> 2, j = l & 3;
  _Float16* eprow =
      (_Float16*)(att +
                  ((size_t)hb * L_ + ltile * 128 + w * 16 + cr) * (size_t)T_) +
      T_;

  // prev prefetch: 2 chunk-batches of 4x f32x4 in flight
  f32x4 pb[2][4];
  auto pload = [&](int c, int s) {
#pragma unroll
    for (int nt = 0; nt < 4; ++nt)
      pb[s][nt] = *(const f32x4*)(prow + c * 64 + nt * 16 + lg * 4);
  };
  pload(0, 0);
  pload(1, 1);

  __syncthreads();   // K staged (prologue only; loop has no block barriers)

  float zsum = 0.f;

#pragma unroll 2
  for (int c = 0; c < 16; ++c) {
    f32x4 pvv[4];
#pragma unroll
    for (int nt = 0; nt < 4; ++nt) pvv[nt] = pb[c & 1][nt];
    if (c < 14) pload(c + 2, c & 1);

#pragma unroll
    for (int nt = 0; nt < 4; ++nt) {
      // swapped QK^T: acc[i] = S^T[t = c*64 + nt*16 + lg*4 + i][q = qrow]
      const int trow = c * 64 + nt * 16 + l15;
      half8 ka0 = *(const half8*)&Ks[trow][lg * 8];
      half8 ka1 = *(const half8*)&Ks[trow][32 + lg * 8];
      f32x4 acc = {0.f, 0.f, 0.f, 0.f};
      acc = __builtin_amdgcn_mfma_f32_16x16x32_f16(ka0, qb2[0], acc, 0, 0, 0);
      acc = __builtin_amdgcn_mfma_f32_16x16x32_f16(ka1, qb2[1], acc, 0, 0, 0);

      float e0 = __expf(acc[0] * SCALE + pvv[nt][0]);
      float e1 = __expf(acc[1] * SCALE + pvv[nt][1]);
      float e2 = __expf(acc[2] * SCALE + pvv[nt][2]);
      float e3 = __expf(acc[3] * SCALE + pvv[nt][3]);
      zsum += (e0 + e1) + (e2 + e3);
      half4 ev;
      ev[0] = (_Float16)e0; ev[1] = (_Float16)e1;
      ev[2] = (_Float16)e2; ev[3] = (_Float16)e3;
      *(half4*)&El[w][l15][nt * 16 + lg * 4] = ev;
    }

    // wave-private copy-out, dense sectors: ha covers bytes [0,64),
    // hb2 covers [64,128) of the row's 128B chunk (full-line writes).
    half8 ha = *(const half8*)&El[w][cr][j * 8];
    half8 hb2 = *(const half8*)&El[w][cr][32 + j * 8];
    *(half8*)(eprow + c * 64 + j * 8) = ha;
    *(half8*)(eprow + c * 64 + 32 + j * 8) = hb2;
  }

  // Z: wave covers all T for its 16 rows -> reduce over lg groups only
  zsum += __shfl_xor(zsum, 16, 64);
  zsum += __shfl_xor(zsum, 32, 64);
  if (lg == 0) out[((size_t)hb * L_ + qrow) * (size_t)D_] = 1.0f / zsum;
}

// ===========================================================================
// Pass 2 (pvpass): 512 threads (8 waves), 128 q-rows/block, grid 8x64.
// The ENTIRE per-hb V^T (f16, [64][1030] = 129KB LDS) staged once; loop vmem
// queue = E loads (depth-4) + att/out stores only. E f16 A-frags direct,
// normalize in f32, att f32 stores from regs, PV MFMA from LDS.
// In-place E-clobber safe (same scheme as r13, re-verified: overlap needs
// c > 18, max is 15). rz from out d=0 slots, then out overwritten.
// ===========================================================================
__global__ __launch_bounds__(512) void pvpass(
    const _Float16* __restrict__ Vh, float* __restrict__ out,
    float* __restrict__ att) {
  __shared__ __align__(16) _Float16 Vt[64][1030];    // 128.75 KB, full-T V^T

  const int ltile = blockIdx.x;   // 0..7
  const int hb    = blockIdx.y;   // 0..63
  const int tid = threadIdx.x;
  const int w = tid >> 6, l = tid & 63, l15 = l & 15, lg = l >> 4;
  const int qrow = ltile * 128 + w * 16 + l15;

  const _Float16* vbh = Vh + (size_t)hb * D_ * T_;  // [d][t] f16

  // ---- stage ALL of V^T: 16 reps x (512 thr x 16B) = 128 KB
  {
    const int d = tid >> 3, tq = (tid & 7) * 8;
#pragma unroll
    for (int rep = 0; rep < 16; ++rep) {
      const int t = rep * 64 + tq;
      *(half8*)&Vt[d][t] = *(const half8*)(vbh + (size_t)d * T_ + t);
    }
  }

  float* arow = att + ((size_t)hb * L_ + qrow) * (size_t)T_;
  const _Float16* erow = (const _Float16*)arow + T_;
  const float rzq = out[((size_t)hb * L_ + qrow) * (size_t)D_];

  half8 eb[4][2];  // depth-4 E prefetch, statically indexed
  auto eload = [&](int c, int s) {
    eb[s][0] = *(const half8*)(erow + c * 64 + lg * 8);
    eb[s][1] = *(const half8*)(erow + c * 64 + 32 + lg * 8);
  };
  eload(0, 0); eload(1, 1); eload(2, 2); eload(3, 3);

  __syncthreads();   // V staged (prologue only)

  f32x4 oacc[4];
#pragma unroll
  for (int nd = 0; nd < 4; ++nd) oacc[nd] = (f32x4){0.f, 0.f, 0.f, 0.f};

#pragma unroll 4
  for (int c = 0; c < 16; ++c) {
    half8 e0 = eb[c & 3][0], e1 = eb[c & 3][1];
    if (c < 12) eload(c + 4, c & 3);

#pragma unroll
    for (int ks = 0; ks < 2; ++ks) {
      half8 ef = ks ? e1 : e0;
      f32x4 s0, s1;
      half8 af;
#pragma unroll
      for (int e = 0; e < 4; ++e) {
        float v0 = (float)ef[e] * rzq;
        float v1 = (float)ef[4 + e] * rzq;
        s0[e] = v0; s1[e] = v1;
        af[e] = (_Float16)v0;
        af[4 + e] = (_Float16)v1;
      }
      *(f32x4*)(arow + c * 64 + ks * 32 + lg * 8) = s0;
      *(f32x4*)(arow + c * 64 + ks * 32 + lg * 8 + 4) = s1;

#pragma unroll
      for (int nd = 0; nd < 4; ++nd) {
        half8 vb =
            *(const half8*)&Vt[nd * 16 + l15][c * 64 + ks * 32 + lg * 8];
        oacc[nd] =
            __builtin_amdgcn_mfma_f32_16x16x32_f16(af, vb, oacc[nd], 0, 0, 0);
      }
    }
  }

  // epilogue: oacc[nd][i] = O[w*16+lg*4+i][nd*16+l15] (already normalized)
  float* outw =
      out + ((size_t)hb * L_ + ltile * 128 + w * 16 + lg * 4) * (size_t)D_;
#pragma unroll
  for (int nd = 0; nd < 4; ++nd)
#pragma unroll
    for (int i = 0; i < 4; ++i)
      outw[(size_t)i * D_ + nd * 16 + l15] = oacc[nd][i];
}

extern "C" void kernel_launch(void* const* d_in, const int* in_sizes, int n_in,
                              void* d_out, int out_size, void* d_ws,
                              size_t ws_size, hipStream_t stream) {
  const float* q    = (const float*)d_in[0];  // (H,B,L,D)
  const float* k    = (const float*)d_in[1];  // (H,B,T,D)
  const float* v    = (const float*)d_in[2];  // (H,B,T,D)
  const float* prev = (const float*)d_in[3];  // (H,B,L,T)

  float* out = (float*)d_out;                 // (H,B,L,D)
  float* att = out + (size_t)HB_ * L_ * D_;   // (H,B,L,T)

  const size_t KV_ELEMS = (size_t)HB_ * T_ * D_;  // 4,194,304
  _Float16* Kh = (_Float16*)d_ws;                 // 8 MB
  _Float16* Vh = Kh + KV_ELEMS;                   // 8 MB (ws >= 16 MB proven)

  cvt_k<<<(int)(KV_ELEMS / (256 * 8)), 256, 0, stream>>>(k, Kh);
  cvt_v<<<dim3(T_ / 128, HB_), 256, 0, stream>>>(v, Vh);

  zpass<<<dim3(L_ / 128, HB_), 512, 0, stream>>>(q, Kh, prev, out, att);
  pvpass<<<dim3(L_ / 128, HB_), 512, 0, stream>>>(Vh, out, att);
}

// Round 15
// 227.999 us; speedup vs baseline: 1.7080x; 1.1366x over previous
//
#include <hip/hip_runtime.h>

#define SCALE 0.125f

constexpr int L_ = 1024, T_ = 1024, D_ = 64, HB_ = 64;

using f32x4 = __attribute__((ext_vector_type(4))) float;
using half8 = __attribute__((ext_vector_type(8))) _Float16;
using half4 = __attribute__((ext_vector_type(4))) _Float16;

// ===========================================================================
// Prologue: V f32 [hb][t][d] -> Vh f16 transposed [hb][d][t]. (r10-proven)
// ===========================================================================
__global__ __launch_bounds__(256) void cvt_v(const float* __restrict__ v,
                                             _Float16* __restrict__ vh) {
  __shared__ _Float16 ts[64][136];
  const int tid = threadIdx.x;
  const int hb = blockIdx.y;
  const int t0 = blockIdx.x * 128;
  {
    const int tr = tid >> 1, dh = (tid & 1) * 32;
    const float* p = v + ((size_t)hb * T_ + t0 + tr) * D_ + dh;
#pragma unroll
    for (int i = 0; i < 8; ++i) {
      f32x4 r = *(const f32x4*)(p + i * 4);
#pragma unroll
      for (int e = 0; e < 4; ++e) ts[dh + i * 4 + e][tr] = (_Float16)r[e];
    }
  }
  __syncthreads();
  {
    const int d = tid >> 2, tq = (tid & 3) * 32;
    _Float16* qo = vh + ((size_t)hb * D_ + d) * T_ + t0 + tq;
#pragma unroll
    for (int i = 0; i < 4; ++i)
      *(half8*)(qo + i * 8) = *(const half8*)&ts[d][tq + i * 8];
  }
}

// ===========================================================================
// Fused kernel: 512 threads (8 waves), 128 q-rows/block, grid 8x64.
// Full per-hb K staged to LDS once (f32->f16 during staging, 140 KB).
// Wave w owns rows w*16..+15, fully independent after staging:
//  Phase 1: QK^T from LDS + prev (HBM stream, depth-2) -> zsum only.
//           Z = 2x shfl_xor; all lanes get their row's 1/Z. No E anywhere.
//  Phase 2: re-read prev (L3-hot), recompute QK^T+exp (identical arithmetic),
//           normalize in f32, stream att stores (dense 64B sectors), PV via
//           wave-private El LDS A-frags + direct f16 V^T loads (issued at
//           chunk top so consuming them never drains the prev prefetch).
// E never touches global memory. One barrier total (after K staging).
// ===========================================================================
__global__ __launch_bounds__(512) void attn_all(
    const float* __restrict__ q, const float* __restrict__ kk,
    const _Float16* __restrict__ Vh, const float* __restrict__ prev,
    float* __restrict__ out, float* __restrict__ att) {
  __shared__ __align__(16) _Float16 Ks[1024][70];   // 143,360 B full-T K
  __shared__ __align__(16) _Float16 El[8][16][72];  // 18,432 B wave-private

  const int ltile = blockIdx.x;   // 0..7
  const int hb    = blockIdx.y;   // 0..63
  const int tid = threadIdx.x;
  const int w = tid >> 6, l = tid & 63, l15 = l & 15, lg = l >> 4;
  const int qrow = ltile * 128 + w * 16 + l15;

  // ---- stage ALL of K (f32 -> f16): 8 reps x (512 thr x 16 floats)
  {
    const int srow = tid >> 2, scol = (tid & 3) * 16;
    const float* kp0 = kk + (size_t)hb * T_ * D_;
#pragma unroll
    for (int rep = 0; rep < 8; ++rep) {
      const int r = rep * 128 + srow;
      const float* p = kp0 + (size_t)r * D_ + scol;
      f32x4 a = *(const f32x4*)(p);
      f32x4 b = *(const f32x4*)(p + 4);
      f32x4 cc = *(const f32x4*)(p + 8);
      f32x4 d = *(const f32x4*)(p + 12);
      half8 h0, h1;
#pragma unroll
      for (int e = 0; e < 4; ++e) {
        h0[e] = (_Float16)a[e];  h0[4 + e] = (_Float16)b[e];
        h1[e] = (_Float16)cc[e]; h1[4 + e] = (_Float16)d[e];
      }
      *(half8*)&Ks[r][scol] = h0;
      *(half8*)&Ks[r][scol + 8] = h1;
    }
  }

  // Q B-frag (swapped QK^T): lane holds Q[qrow][f*32 + lg*8 + e]
  half8 qb2[2];
  {
    const float* qp = q + ((size_t)hb * L_ + qrow) * D_ + lg * 8;
#pragma unroll
    for (int f = 0; f < 2; ++f)
#pragma unroll
      for (int e = 0; e < 8; ++e) qb2[f][e] = (_Float16)qp[f * 32 + e];
  }

  const float* prow = prev + ((size_t)hb * L_ + qrow) * (size_t)T_;

  f32x4 pb[2][4];
  auto pload = [&](int c, int s) {
#pragma unroll
    for (int nt = 0; nt < 4; ++nt)
      pb[s][nt] = *(const f32x4*)(prow + c * 64 + nt * 16 + lg * 4);
  };

  __syncthreads();   // K staged; no further block barriers

  // ======================= Phase 1: Z only ================================
  pload(0, 0);
  pload(1, 1);
  float zsum = 0.f;

#pragma unroll 2
  for (int c = 0; c < 16; ++c) {
    f32x4 pvv[4];
#pragma unroll
    for (int nt = 0; nt < 4; ++nt) pvv[nt] = pb[c & 1][nt];
    if (c < 14) pload(c + 2, c & 1);

#pragma unroll
    for (int nt = 0; nt < 4; ++nt) {
      const int trow = c * 64 + nt * 16 + l15;
      half8 ka0 = *(const half8*)&Ks[trow][lg * 8];
      half8 ka1 = *(const half8*)&Ks[trow][32 + lg * 8];
      f32x4 acc = {0.f, 0.f, 0.f, 0.f};
      acc = __builtin_amdgcn_mfma_f32_16x16x32_f16(ka0, qb2[0], acc, 0, 0, 0);
      acc = __builtin_amdgcn_mfma_f32_16x16x32_f16(ka1, qb2[1], acc, 0, 0, 0);
      zsum += __expf(acc[0] * SCALE + pvv[nt][0]);
      zsum += __expf(acc[1] * SCALE + pvv[nt][1]);
      zsum += __expf(acc[2] * SCALE + pvv[nt][2]);
      zsum += __expf(acc[3] * SCALE + pvv[nt][3]);
    }
  }

  // Z for row l15: reduce the 4 lg lanes; result lands in ALL lanes
  zsum += __shfl_xor(zsum, 16, 64);
  zsum += __shfl_xor(zsum, 32, 64);
  const float rzq = 1.0f / zsum;

  // ======================= Phase 2: att + PV ==============================
  const _Float16* vbh = Vh + (size_t)hb * D_ * T_;  // [d][t] f16
  float* arow = att + ((size_t)hb * L_ + qrow) * (size_t)T_;

  pload(0, 0);   // re-read (L3-hot)
  pload(1, 1);

  f32x4 oacc[4];
#pragma unroll
  for (int nd = 0; nd < 4; ++nd) oacc[nd] = (f32x4){0.f, 0.f, 0.f, 0.f};

#pragma unroll 2
  for (int c = 0; c < 16; ++c) {
    // V fragment loads FIRST (so consuming them never drains younger prev)
    half8 vr[8];
#pragma unroll
    for (int ks = 0; ks < 2; ++ks)
#pragma unroll
      for (int nd = 0; nd < 4; ++nd)
        vr[ks * 4 + nd] = *(const half8*)(vbh + (size_t)(nd * 16 + l15) * T_ +
                                          c * 64 + ks * 32 + lg * 8);

    f32x4 pvv[4];
#pragma unroll
    for (int nt = 0; nt < 4; ++nt) pvv[nt] = pb[c & 1][nt];
    if (c < 14) pload(c + 2, c & 1);

    // recompute scores, normalize, stream att, build El
#pragma unroll
    for (int nt = 0; nt < 4; ++nt) {
      const int trow = c * 64 + nt * 16 + l15;
      half8 ka0 = *(const half8*)&Ks[trow][lg * 8];
      half8 ka1 = *(const half8*)&Ks[trow][32 + lg * 8];
      f32x4 acc = {0.f, 0.f, 0.f, 0.f};
      acc = __builtin_amdgcn_mfma_f32_16x16x32_f16(ka0, qb2[0], acc, 0, 0, 0);
      acc = __builtin_amdgcn_mfma_f32_16x16x32_f16(ka1, qb2[1], acc, 0, 0, 0);

      f32x4 s;
      s[0] = __expf(acc[0] * SCALE + pvv[nt][0]) * rzq;
      s[1] = __expf(acc[1] * SCALE + pvv[nt][1]) * rzq;
      s[2] = __expf(acc[2] * SCALE + pvv[nt][2]) * rzq;
      s[3] = __expf(acc[3] * SCALE + pvv[nt][3]) * rzq;
      *(f32x4*)(arow + c * 64 + nt * 16 + lg * 4) = s;

      half4 ev;
      ev[0] = (_Float16)s[0]; ev[1] = (_Float16)s[1];
      ev[2] = (_Float16)s[2]; ev[3] = (_Float16)s[3];
      *(half4*)&El[w][l15][nt * 16 + lg * 4] = ev;
    }

    // PV: A-frag from El (same-wave DS in-order), B-frag = vr
#pragma unroll
    for (int ks = 0; ks < 2; ++ks) {
      half8 af = *(const half8*)&El[w][l15][ks * 32 + lg * 8];
#pragma unroll
      for (int nd = 0; nd < 4; ++nd)
        oacc[nd] = __builtin_amdgcn_mfma_f32_16x16x32_f16(af, vr[ks * 4 + nd],
                                                          oacc[nd], 0, 0, 0);
    }
  }

  // epilogue: oacc[nd][i] = O[q = w*16 + lg*4 + i][d = nd*16 + l15]
  float* outw =
      out + ((size_t)hb * L_ + ltile * 128 + w * 16 + lg * 4) * (size_t)D_;
#pragma unroll
  for (int nd = 0; nd < 4; ++nd)
#pragma unroll
    for (int i = 0; i < 4; ++i)
      outw[(size_t)i * D_ + nd * 16 + l15] = oacc[nd][i];
}

extern "C" void kernel_launch(void* const* d_in, const int* in_sizes, int n_in,
                              void* d_out, int out_size, void* d_ws,
                              size_t ws_size, hipStream_t stream) {
  const float* q    = (const float*)d_in[0];  // (H,B,L,D)
  const float* k    = (const float*)d_in[1];  // (H,B,T,D)
  const float* v    = (const float*)d_in[2];  // (H,B,T,D)
  const float* prev = (const float*)d_in[3];  // (H,B,L,T)

  float* out = (float*)d_out;                 // (H,B,L,D)
  float* att = out + (size_t)HB_ * L_ * D_;   // (H,B,L,T)

  _Float16* Vh = (_Float16*)d_ws;             // 8 MB (ws >= 16 MB proven)

  cvt_v<<<dim3(T_ / 128, HB_), 256, 0, stream>>>(v, Vh);
  attn_all<<<dim3(L_ / 128, HB_), 512, 0, stream>>>(q, k, Vh, prev, out, att);
}